// Round 11
// baseline (62.220 us; speedup 1.0000x reference)
//
#include <hip/hip_runtime.h>
#include <math.h>

#define BB 16
#define TT 128
#define MM 32
#define PP 64
#define CC 256

typedef float f32x4 __attribute__((ext_vector_type(4)));

// ---- K1: per (b,m), 512 threads: w_in, eff_c(+nrm), eff_p, matvec, MLP ----
__global__ __launch_bounds__(512) void K1_front(
        const float* __restrict__ pointers,
        const float* __restrict__ contents,
        const float* __restrict__ receivers,
        const float* __restrict__ memories,
        const float* __restrict__ W1,
        const float* __restrict__ b1,
        const float* __restrict__ W2,
        const float* __restrict__ b2,
        float* __restrict__ nrm_ws,
        float* __restrict__ outp_g,
        float* __restrict__ outc_g) {
    const int bm = blockIdx.x;
    const int b = bm >> 5, m = bm & 31;
    const int tid = threadIdx.x;
    const int lane = tid & 63, w = tid >> 6;

    __shared__ float w_in[TT];
    __shared__ __align__(16) float ri[PP + CC];   // [eff_p | eff_c]
    __shared__ float partc[4][CC];
    __shared__ float part8[8][PP];
    __shared__ float h[PP];
    __shared__ float outc_s[CC];
    __shared__ float red[4];

    // ---- w_in: 4 lanes per token, contiguous float4 reads ----
    {
        const int t = tid >> 2, q = tid & 3;
        const float4* pr4 = reinterpret_cast<const float4*>(pointers + (b * TT + t) * PP + q * 16);
        const float4* rc4 = reinterpret_cast<const float4*>(receivers + m * PP + q * 16);
        float s = 0.f;
        #pragma unroll
        for (int k = 0; k < 4; ++k) {
            float4 v = pr4[k], rv = rc4[k];
            s += v.x * rv.x + v.y * rv.y + v.z * rv.z + v.w * rv.w;
        }
        s += __shfl_xor(s, 1, 64);
        s += __shfl_xor(s, 2, 64);
        if (q == 0) {
            float th = tanhf(s);
            w_in[t] = th > 0.f ? th : 0.f;
        }
    }
    __syncthreads();
    // ---- eff_c partials: float2 column-pairs, 4 t-groups of 32 ----
    {
        const int cp = tid & 127, g = tid >> 7;
        const float2* cb2 = reinterpret_cast<const float2*>(contents + (b * TT + g * 32) * CC) + cp;
        float2 acc = {0.f, 0.f};
        #pragma unroll 8
        for (int t = 0; t < 32; ++t) {
            float2 v = cb2[t * 128];
            const float ww = w_in[g * 32 + t];
            acc.x += ww * v.x;
            acc.y += ww * v.y;
        }
        partc[g][2 * cp]     = acc.x;
        partc[g][2 * cp + 1] = acc.y;
    }
    // ---- eff_p partials: p = tid&63, 8 t-groups of 16 ----
    {
        const int p = tid & 63, g = tid >> 6;
        const float* pb = pointers + (b * TT + g * 16) * PP + p;
        float acc = 0.f;
        #pragma unroll
        for (int t = 0; t < 16; ++t) acc += w_in[g * 16 + t] * pb[t * PP];
        part8[g][p] = acc;
    }
    __syncthreads();
    float ecv = 0.f;
    if (tid < CC) {
        ecv = partc[0][tid] + partc[1][tid] + partc[2][tid] + partc[3][tid];
        ri[PP + tid] = ecv;
        float v = ecv * ecv;
        #pragma unroll
        for (int off = 32; off; off >>= 1) v += __shfl_xor(v, off, 64);
        if (lane == 0) red[w] = v;
    } else if (tid < CC + PP) {
        const int p = tid - CC;
        float a = 0.f;
        #pragma unroll
        for (int g = 0; g < 8; ++g) a += part8[g][p];
        ri[p] = a;
    }
    __syncthreads();
    if (tid < CC) {
        const float ss = red[0] + red[1] + red[2] + red[3];
        nrm_ws[bm * CC + tid] = ecv / (ss + 1e-42f);
    }

    // ---- out_c = mem[m] @ eff_c: 16 lanes/row, 4 rows per wave-iter ----
    {
        const int g = lane >> 4, j = lane & 15;
        float4 e_reg[4];
        #pragma unroll
        for (int k = 0; k < 4; ++k)
            e_reg[k] = *reinterpret_cast<const float4*>(&ri[PP + 4 * (j + 16 * k)]);
        const float4* mem4 = reinterpret_cast<const float4*>(memories) + m * (CC * CC / 4);
        #pragma unroll
        for (int i = 0; i < 8; ++i) {
            const int c = w * 32 + i * 4 + g;
            const float4* row4 = mem4 + c * 64;
            float s = 0.f;
            #pragma unroll
            for (int k = 0; k < 4; ++k) {
                float4 mv = row4[j + 16 * k];
                s += mv.x * e_reg[k].x + mv.y * e_reg[k].y
                   + mv.z * e_reg[k].z + mv.w * e_reg[k].w;
            }
            s += __shfl_xor(s, 1, 64);
            s += __shfl_xor(s, 2, 64);
            s += __shfl_xor(s, 4, 64);
            s += __shfl_xor(s, 8, 64);
            if (j == 0) outc_s[c] = s;
        }
    }

    // ---- MLP layer 1 ----
    {
        const float* w1 = W1 + m * 320 * 64;
        float acc = 0.f;
        const int i0 = w * 40;
        #pragma unroll 8
        for (int i = i0; i < i0 + 40; ++i) acc += ri[i] * w1[i * 64 + lane];
        __syncthreads();               // also covers outc_s completion
        part8[w][lane] = acc;
    }
    __syncthreads();
    if (tid < PP) {
        float s = b1[m * PP + tid];
        #pragma unroll
        for (int g = 0; g < 8; ++g) s += part8[g][tid];
        h[tid] = s > 0.f ? s : 0.f;
    }
    __syncthreads();
    // ---- MLP layer 2 ----
    {
        const float* w2 = W2 + m * 64 * 64;
        float acc = 0.f;
        const int i0 = w * 8;
        #pragma unroll
        for (int i = i0; i < i0 + 8; ++i) acc += h[i] * w2[i * 64 + lane];
        part8[w][lane] = acc;
    }
    __syncthreads();
    if (tid < PP) {
        float s = b2[m * PP + tid];
        #pragma unroll
        for (int g = 0; g < 8; ++g) s += part8[g][tid];
        outp_g[bm * PP + tid] = s > 0.f ? s : 0.f;
    }
    if (tid < CC) outc_g[bm * CC + tid] = outc_s[tid];
}

// ---- K3: fused route+stream, 64-row tiles (unchanged from R10) ------------
__global__ __launch_bounds__(256) void K3_fused(
        const float* __restrict__ memories,
        const float* __restrict__ outp_g,
        const float* __restrict__ outc_g,
        const float* __restrict__ nrm_ws,
        float* __restrict__ mems_out) {
    const int gid = blockIdx.x;
    const int b = gid >> 7;
    const int m = (gid >> 2) & 31, cs = gid & 3;
    const int bm = b * MM + m;
    const int tid = threadIdx.x;
    const int lane = tid & 63, w = tid >> 6;

    __shared__ float wout_s[MM];
    __shared__ float eoc_s[64];

    {
        const int n = tid >> 3, j = tid & 7;
        const float* opm = outp_g + bm * PP + j * 8;
        const float* opn = outp_g + (b * MM + n) * PP + j * 8;
        float s = 0.f;
        #pragma unroll
        for (int k = 0; k < 8; ++k) s += opm[k] * opn[k];
        s += __shfl_xor(s, 1, 64);
        s += __shfl_xor(s, 2, 64);
        s += __shfl_xor(s, 4, 64);
        if (j == 0) {
            float th = tanhf(s);
            wout_s[n] = th > 0.f ? th : 0.f;
        }
    }
    const float4 nv = *reinterpret_cast<const float4*>(nrm_ws + bm * CC + lane * 4);
    __syncthreads();
    {
        const int c_local = tid >> 2, k = tid & 3;
        const int c = cs * 64 + c_local;
        const float* cb = outc_g + (b * MM + k * 8) * CC + c;
        float s = 0.f;
        #pragma unroll
        for (int kk = 0; kk < 8; ++kk)
            s += wout_s[k * 8 + kk] * cb[kk * CC];
        s += __shfl_xor(s, 1, 64);
        s += __shfl_xor(s, 2, 64);
        if (k == 0) eoc_s[c_local] = s;
    }
    __syncthreads();

    const f32x4* mem4 = reinterpret_cast<const f32x4*>(memories) + (m * CC + cs * 64) * 64;
    f32x4* out4 = reinterpret_cast<f32x4*>(mems_out) + (bm * CC + cs * 64) * 64;

    #pragma unroll
    for (int it = 0; it < 16; ++it) {
        const int idx = it * 256 + tid;
        const float e = eoc_s[it * 4 + w];
        f32x4 mv = mem4[idx];
        f32x4 o;
        o.x = 0.5f * (mv.x + e * nv.x);
        o.y = 0.5f * (mv.y + e * nv.y);
        o.z = 0.5f * (mv.z + e * nv.z);
        o.w = 0.5f * (mv.w + e * nv.w);
        __builtin_nontemporal_store(o, &out4[idx]);
    }
}

extern "C" void kernel_launch(void* const* d_in, const int* in_sizes, int n_in,
                              void* d_out, int out_size, void* d_ws, size_t ws_size,
                              hipStream_t stream) {
    const float* pointers  = (const float*)d_in[0];
    const float* contents  = (const float*)d_in[1];
    const float* receivers = (const float*)d_in[2];
    const float* memories  = (const float*)d_in[3];
    const float* W1 = (const float*)d_in[4];
    const float* b1 = (const float*)d_in[5];
    const float* W2 = (const float*)d_in[6];
    const float* b2 = (const float*)d_in[7];

    float* out      = (float*)d_out;
    float* outp_g   = out;                       // 16*32*64
    float* outc_g   = out + 32768;               // 16*32*256
    float* mems_out = out + 32768 + 131072;      // 16*32*256*256

    float* ws     = (float*)d_ws;
    float* nrm    = ws;                // 131072
    float* nrm_x  = ws + 131072;       // 131072 (shadow)
    float* outp_x = ws + 262144;       // 32768  (shadow)
    float* outc_x = ws + 294912;       // 131072 (shadow)

    // INSTRUMENTATION: shadow K1 (identical work, ws-only outputs) to measure
    // K1's steady-state duration as (dur - 47.7 - gap). Deterministic.
    hipLaunchKernelGGL(K1_front, dim3(BB * MM), dim3(512), 0, stream,
                       pointers, contents, receivers, memories, W1, b1, W2, b2,
                       nrm_x, outp_x, outc_x);
    hipLaunchKernelGGL(K1_front, dim3(BB * MM), dim3(512), 0, stream,
                       pointers, contents, receivers, memories, W1, b1, W2, b2,
                       nrm, outp_g, outc_g);
    hipLaunchKernelGGL(K3_fused, dim3(BB * MM * 4), dim3(256), 0, stream,
                       memories, outp_g, outc_g, nrm, mems_out);
}

// Round 12
// 47.009 us; speedup vs baseline: 1.3236x; 1.3236x over previous
//
#include <hip/hip_runtime.h>
#include <math.h>

#define BB 16
#define TT 128
#define MM 32
#define PP 64
#define CC 256

typedef float f32x4 __attribute__((ext_vector_type(4)));

// ---- K1: per (b,m), 512 threads: w_in, eff_c(+nrm), eff_p, matvec, MLP ----
__global__ __launch_bounds__(512) void K1_front(
        const float* __restrict__ pointers,
        const float* __restrict__ contents,
        const float* __restrict__ receivers,
        const float* __restrict__ memories,
        const float* __restrict__ W1,
        const float* __restrict__ b1,
        const float* __restrict__ W2,
        const float* __restrict__ b2,
        float* __restrict__ nrm_ws,
        float* __restrict__ outp_g,
        float* __restrict__ outc_g) {
    const int bm = blockIdx.x;
    const int b = bm >> 5, m = bm & 31;
    const int tid = threadIdx.x;
    const int lane = tid & 63, w = tid >> 6;

    __shared__ float w_in[TT];
    __shared__ __align__(16) float ri[PP + CC];   // [eff_p | eff_c]
    __shared__ float partc[4][CC];
    __shared__ float part8[8][PP];
    __shared__ float h[PP];
    __shared__ float outc_s[CC];
    __shared__ float red[4];

    // ---- w_in: 4 lanes per token, contiguous float4 reads ----
    {
        const int t = tid >> 2, q = tid & 3;
        const float4* pr4 = reinterpret_cast<const float4*>(pointers + (b * TT + t) * PP + q * 16);
        const float4* rc4 = reinterpret_cast<const float4*>(receivers + m * PP + q * 16);
        float s = 0.f;
        #pragma unroll
        for (int k = 0; k < 4; ++k) {
            float4 v = pr4[k], rv = rc4[k];
            s += v.x * rv.x + v.y * rv.y + v.z * rv.z + v.w * rv.w;
        }
        s += __shfl_xor(s, 1, 64);
        s += __shfl_xor(s, 2, 64);
        if (q == 0) {
            float th = tanhf(s);
            w_in[t] = th > 0.f ? th : 0.f;
        }
    }
    __syncthreads();
    // ---- eff_c partials: float2 column-pairs, 4 t-groups of 32 ----
    {
        const int cp = tid & 127, g = tid >> 7;
        const float2* cb2 = reinterpret_cast<const float2*>(contents + (b * TT + g * 32) * CC) + cp;
        float2 acc = {0.f, 0.f};
        #pragma unroll 8
        for (int t = 0; t < 32; ++t) {
            float2 v = cb2[t * 128];
            const float ww = w_in[g * 32 + t];
            acc.x += ww * v.x;
            acc.y += ww * v.y;
        }
        partc[g][2 * cp]     = acc.x;
        partc[g][2 * cp + 1] = acc.y;
    }
    // ---- eff_p partials: p = tid&63, 8 t-groups of 16 ----
    {
        const int p = tid & 63, g = tid >> 6;
        const float* pb = pointers + (b * TT + g * 16) * PP + p;
        float acc = 0.f;
        #pragma unroll
        for (int t = 0; t < 16; ++t) acc += w_in[g * 16 + t] * pb[t * PP];
        part8[g][p] = acc;
    }
    __syncthreads();
    float ecv = 0.f;
    if (tid < CC) {
        ecv = partc[0][tid] + partc[1][tid] + partc[2][tid] + partc[3][tid];
        ri[PP + tid] = ecv;
        float v = ecv * ecv;
        #pragma unroll
        for (int off = 32; off; off >>= 1) v += __shfl_xor(v, off, 64);
        if (lane == 0) red[w] = v;
    } else if (tid < CC + PP) {
        const int p = tid - CC;
        float a = 0.f;
        #pragma unroll
        for (int g = 0; g < 8; ++g) a += part8[g][p];
        ri[p] = a;
    }
    __syncthreads();
    if (tid < CC) {
        const float ss = red[0] + red[1] + red[2] + red[3];
        nrm_ws[bm * CC + tid] = ecv / (ss + 1e-42f);
    }

    // ---- out_c = mem[m] @ eff_c: 16 lanes/row, 4 rows per wave-iter ----
    {
        const int g = lane >> 4, j = lane & 15;
        float4 e_reg[4];
        #pragma unroll
        for (int k = 0; k < 4; ++k)
            e_reg[k] = *reinterpret_cast<const float4*>(&ri[PP + 4 * (j + 16 * k)]);
        const float4* mem4 = reinterpret_cast<const float4*>(memories) + m * (CC * CC / 4);
        #pragma unroll
        for (int i = 0; i < 8; ++i) {
            const int c = w * 32 + i * 4 + g;
            const float4* row4 = mem4 + c * 64;
            float s = 0.f;
            #pragma unroll
            for (int k = 0; k < 4; ++k) {
                float4 mv = row4[j + 16 * k];
                s += mv.x * e_reg[k].x + mv.y * e_reg[k].y
                   + mv.z * e_reg[k].z + mv.w * e_reg[k].w;
            }
            s += __shfl_xor(s, 1, 64);
            s += __shfl_xor(s, 2, 64);
            s += __shfl_xor(s, 4, 64);
            s += __shfl_xor(s, 8, 64);
            if (j == 0) outc_s[c] = s;
        }
    }

    // ---- MLP layer 1 ----
    {
        const float* w1 = W1 + m * 320 * 64;
        float acc = 0.f;
        const int i0 = w * 40;
        #pragma unroll 8
        for (int i = i0; i < i0 + 40; ++i) acc += ri[i] * w1[i * 64 + lane];
        __syncthreads();               // also covers outc_s completion
        part8[w][lane] = acc;
    }
    __syncthreads();
    if (tid < PP) {
        float s = b1[m * PP + tid];
        #pragma unroll
        for (int g = 0; g < 8; ++g) s += part8[g][tid];
        h[tid] = s > 0.f ? s : 0.f;
    }
    __syncthreads();
    // ---- MLP layer 2 ----
    {
        const float* w2 = W2 + m * 64 * 64;
        float acc = 0.f;
        const int i0 = w * 8;
        #pragma unroll
        for (int i = i0; i < i0 + 8; ++i) acc += h[i] * w2[i * 64 + lane];
        part8[w][lane] = acc;
    }
    __syncthreads();
    if (tid < PP) {
        float s = b2[m * PP + tid];
        #pragma unroll
        for (int g = 0; g < 8; ++g) s += part8[g][tid];
        outp_g[bm * PP + tid] = s > 0.f ? s : 0.f;
    }
    if (tid < CC) outc_g[bm * CC + tid] = outc_s[tid];
}

// ---- K3: fused route+stream, 64-row tiles; NORMAL stores (A/B vs NT) ------
__global__ __launch_bounds__(256) void K3_fused(
        const float* __restrict__ memories,
        const float* __restrict__ outp_g,
        const float* __restrict__ outc_g,
        const float* __restrict__ nrm_ws,
        float* __restrict__ mems_out) {
    const int gid = blockIdx.x;
    const int b = gid >> 7;
    const int m = (gid >> 2) & 31, cs = gid & 3;
    const int bm = b * MM + m;
    const int tid = threadIdx.x;
    const int lane = tid & 63, w = tid >> 6;

    __shared__ float wout_s[MM];
    __shared__ float eoc_s[64];

    {
        const int n = tid >> 3, j = tid & 7;
        const float* opm = outp_g + bm * PP + j * 8;
        const float* opn = outp_g + (b * MM + n) * PP + j * 8;
        float s = 0.f;
        #pragma unroll
        for (int k = 0; k < 8; ++k) s += opm[k] * opn[k];
        s += __shfl_xor(s, 1, 64);
        s += __shfl_xor(s, 2, 64);
        s += __shfl_xor(s, 4, 64);
        if (j == 0) {
            float th = tanhf(s);
            wout_s[n] = th > 0.f ? th : 0.f;
        }
    }
    const float4 nv = *reinterpret_cast<const float4*>(nrm_ws + bm * CC + lane * 4);
    __syncthreads();
    {
        const int c_local = tid >> 2, k = tid & 3;
        const int c = cs * 64 + c_local;
        const float* cb = outc_g + (b * MM + k * 8) * CC + c;
        float s = 0.f;
        #pragma unroll
        for (int kk = 0; kk < 8; ++kk)
            s += wout_s[k * 8 + kk] * cb[kk * CC];
        s += __shfl_xor(s, 1, 64);
        s += __shfl_xor(s, 2, 64);
        if (k == 0) eoc_s[c_local] = s;
    }
    __syncthreads();

    const f32x4* mem4 = reinterpret_cast<const f32x4*>(memories) + (m * CC + cs * 64) * 64;
    f32x4* out4 = reinterpret_cast<f32x4*>(mems_out) + (bm * CC + cs * 64) * 64;

    #pragma unroll
    for (int it = 0; it < 16; ++it) {
        const int idx = it * 256 + tid;
        const float e = eoc_s[it * 4 + w];
        f32x4 mv = mem4[idx];
        f32x4 o;
        o.x = 0.5f * (mv.x + e * nv.x);
        o.y = 0.5f * (mv.y + e * nv.y);
        o.z = 0.5f * (mv.z + e * nv.z);
        o.w = 0.5f * (mv.w + e * nv.w);
        out4[idx] = o;                 // normal store (was NT)
    }
}

extern "C" void kernel_launch(void* const* d_in, const int* in_sizes, int n_in,
                              void* d_out, int out_size, void* d_ws, size_t ws_size,
                              hipStream_t stream) {
    const float* pointers  = (const float*)d_in[0];
    const float* contents  = (const float*)d_in[1];
    const float* receivers = (const float*)d_in[2];
    const float* memories  = (const float*)d_in[3];
    const float* W1 = (const float*)d_in[4];
    const float* b1 = (const float*)d_in[5];
    const float* W2 = (const float*)d_in[6];
    const float* b2 = (const float*)d_in[7];

    float* out      = (float*)d_out;
    float* outp_g   = out;                       // 16*32*64
    float* outc_g   = out + 32768;               // 16*32*256
    float* mems_out = out + 32768 + 131072;      // 16*32*256*256

    float* nrm = (float*)d_ws;                   // 131072 floats

    hipLaunchKernelGGL(K1_front, dim3(BB * MM), dim3(512), 0, stream,
                       pointers, contents, receivers, memories, W1, b1, W2, b2,
                       nrm, outp_g, outc_g);
    hipLaunchKernelGGL(K3_fused, dim3(BB * MM * 4), dim3(256), 0, stream,
                       memories, outp_g, outc_g, nrm, mems_out);
}